// Round 1
// 813.110 us; speedup vs baseline: 1.1346x; 1.1346x over previous
//
#include <hip/hip_runtime.h>

#define LR 0.01f

// Problem constants (from reference setup_inputs): B=4, S=2048, D=1024, Ds=256
constexpr int Bc  = 4;
constexpr int Sc  = 2048;
constexpr int Dc  = 1024;
constexpr int Dsc = 256;

// ---------------------------------------------------------------------------
// Tiled fp32 GEMM:  C[M,N] = A[M,K] @ Bm[K,N] + bias[N] (+ resid[M,N] if given)
// Block: 256 threads, 64x64 tile, BK=16, 4x4 micro-tile per thread.
// ---------------------------------------------------------------------------
__global__ __launch_bounds__(256) void gemm_bias(
    const float* __restrict__ A, const float* __restrict__ Bm,
    const float* __restrict__ bias, const float* __restrict__ resid,
    float* __restrict__ C, int M, int N, int K) {
  constexpr int BM = 64, BN = 64, BK = 16;
  __shared__ float As[BK][BM + 4];
  __shared__ float Bs[BK][BN + 4];

  const int bm = blockIdx.y * BM;
  const int bn = blockIdx.x * BN;
  const int tx = threadIdx.x & 15;   // 0..15 -> 4 cols each
  const int ty = threadIdx.x >> 4;   // 0..15 -> 4 rows each

  float acc[4][4] = {};

  for (int k0 = 0; k0 < K; k0 += BK) {
    // Load A tile: rows bm..bm+63, cols k0..k0+15  (k fastest -> 64B segments)
    for (int i = threadIdx.x; i < BM * BK; i += 256) {
      int m = i >> 4, k = i & 15;
      As[k][m] = A[(size_t)(bm + m) * K + k0 + k];
    }
    // Load B tile: rows k0..k0+15, cols bn..bn+63 (n fastest -> coalesced)
    for (int i = threadIdx.x; i < BK * BN; i += 256) {
      int k = i >> 6, n = i & 63;
      Bs[k][n] = Bm[(size_t)(k0 + k) * N + bn + n];
    }
    __syncthreads();
#pragma unroll
    for (int k = 0; k < BK; ++k) {
      float a[4], bb[4];
#pragma unroll
      for (int i = 0; i < 4; ++i) a[i] = As[k][ty * 4 + i];
#pragma unroll
      for (int j = 0; j < 4; ++j) bb[j] = Bs[k][tx * 4 + j];
#pragma unroll
      for (int i = 0; i < 4; ++i)
#pragma unroll
        for (int j = 0; j < 4; ++j) acc[i][j] += a[i] * bb[j];
    }
    __syncthreads();
  }

#pragma unroll
  for (int i = 0; i < 4; ++i) {
    int m = bm + ty * 4 + i;
#pragma unroll
    for (int j = 0; j < 4; ++j) {
      int n = bn + tx * 4 + j;
      float v = acc[i][j] + bias[n];
      if (resid) v += resid[(size_t)m * N + n];
      C[(size_t)m * N + n] = v;
    }
  }
}

// ---------------------------------------------------------------------------
// TTT scan. 1024 independent sequential chains (one per (b, output-col j)),
// one wave per chain; the 256-float W-column lives in 4 VGPRs per lane.
//
// v2: the per-step critical path was 7 serial cross-lane DS ops
// (6x shfl_xor reduce + 1x shfl for f_j) at ~120cyc each = ~823 cyc/step
// measured. Replace with:
//   - DPP reduction (row_shr:1/2/4/8 + row_bcast:15/31), VALU-latency moves
//   - v_readlane(q, 63) for pred, v_readlane(f0, jl) for f_j
//   - per-wave slot rotation (o_m = 64*((jw+m)&3)) so f_j is ALWAYS in
//     slot 0 at lane jl -> no register-select, no shuffle
//   - prefetch distance 4 (four named buffer sets, unrolled x4) so the
//     ~200cyc L2 load latency stays off the now-short critical path
// ---------------------------------------------------------------------------

template <int CTRL, int RM>
__device__ __forceinline__ float dpp_sum(float v) {
  // v += dpp_move(v); lanes masked off / invalid sources contribute old=0.
  int moved = __builtin_amdgcn_update_dpp(0, __float_as_int(v), CTRL, RM, 0xF, false);
  return v + __int_as_float(moved);
}

__global__ __launch_bounds__(256) void ttt_scan(const float* __restrict__ feat,
                                                float* __restrict__ preds) {
  const int lane = threadIdx.x & 63;
  const int wave = threadIdx.x >> 6;
  const int gw = blockIdx.x * 4 + wave;  // 0 .. B*Ds-1
  const int b = gw >> 8;                 // Ds = 256
  const int j = gw & 255;
  const int jl = j & 63;
  const int jw = j >> 6;

  // Rotated slot offsets: slot m holds f[lane + o_m]; slot 0 contains the
  // 64-group that includes index j, so f_j == readlane(f0, jl).
  const int o0 = 64 * ((jw + 0) & 3);
  const int o1 = 64 * ((jw + 1) & 3);
  const int o2 = 64 * ((jw + 2) & 3);
  const int o3 = 64 * ((jw + 3) & 3);

  const float* fb = feat + (size_t)b * Sc * Dsc + lane;
  float* pb = preds + (size_t)b * Sc * Dsc + j;

  float w0 = 0.f, w1 = 0.f, w2 = 0.f, w3 = 0.f;

  // Preload rows t = 0..3 (prefetch distance 4).
  const float* r0 = fb;
  const float* r1 = fb + Dsc;
  const float* r2 = fb + 2 * Dsc;
  const float* r3 = fb + 3 * Dsc;
  float A0 = r0[o0], A1 = r0[o1], A2 = r0[o2], A3 = r0[o3];
  float B0 = r1[o0], B1 = r1[o1], B2 = r1[o2], B3 = r1[o3];
  float C0 = r2[o0], C1 = r2[o1], C2 = r2[o2], C3 = r2[o3];
  float D0 = r3[o0], D1 = r3[o1], D2 = r3[o2], D3 = r3[o3];

#define TTT_STEP(T, F0, F1, F2, F3)                                            \
  {                                                                            \
    float f0 = F0, f1 = F1, f2 = F2, f3 = F3;                                  \
    if ((T) + 4 < Sc) { /* prefetch row T+4 into this buffer set */            \
      const float* fr = fb + (size_t)((T) + 4) * Dsc;                          \
      F0 = fr[o0]; F1 = fr[o1]; F2 = fr[o2]; F3 = fr[o3];                      \
    }                                                                          \
    /* pred_j = f_t . w_col  (2-level FMA tree, then DPP reduce to lane 63) */ \
    float q = fmaf(f1, w1, f0 * w0) + fmaf(f3, w3, f2 * w2);                   \
    q = dpp_sum<0x111, 0xF>(q); /* row_shr:1  */                               \
    q = dpp_sum<0x112, 0xF>(q); /* row_shr:2  */                               \
    q = dpp_sum<0x114, 0xF>(q); /* row_shr:4  */                               \
    q = dpp_sum<0x118, 0xF>(q); /* row_shr:8  -> lane15/31/47/63 = row sums */ \
    q = dpp_sum<0x142, 0xA>(q); /* row_bcast:15 -> lane31/63 = half sums */    \
    q = dpp_sum<0x143, 0xC>(q); /* row_bcast:31 -> lane63 = full sum */        \
    float p  = __int_as_float(__builtin_amdgcn_readlane(__float_as_int(q), 63)); \
    float fj = __int_as_float(__builtin_amdgcn_readlane(__float_as_int(f0), jl)); \
    float e = LR * (p - fj);                                                   \
    if (lane == 0) pb[(size_t)(T)*Dsc] = p;                                    \
    w0 = fmaf(-e, f0, w0);                                                     \
    w1 = fmaf(-e, f1, w1);                                                     \
    w2 = fmaf(-e, f2, w2);                                                     \
    w3 = fmaf(-e, f3, w3);                                                     \
  }

  for (int t0 = 0; t0 < Sc; t0 += 4) {
    TTT_STEP(t0 + 0, A0, A1, A2, A3);
    TTT_STEP(t0 + 1, B0, B1, B2, B3);
    TTT_STEP(t0 + 2, C0, C1, C2, C3);
    TTT_STEP(t0 + 3, D0, D1, D2, D3);
  }
#undef TTT_STEP
}

extern "C" void kernel_launch(void* const* d_in, const int* in_sizes, int n_in,
                              void* d_out, int out_size, void* d_ws, size_t ws_size,
                              hipStream_t stream) {
  const float* x  = (const float*)d_in[0];  // (B,S,D)
  const float* Wd = (const float*)d_in[1];  // (D,Ds)
  const float* bd = (const float*)d_in[2];  // (Ds)
  const float* Wu = (const float*)d_in[3];  // (Ds,D)
  const float* bu = (const float*)d_in[4];  // (D)
  float* out = (float*)d_out;               // (B,S,D)

  float* feat  = (float*)d_ws;                        // B*S*Ds f32 = 8 MB
  float* preds = feat + (size_t)Bc * Sc * Dsc;        // B*S*Ds f32 = 8 MB

  const int M = Bc * Sc;  // 8192
  dim3 blk(256);

  // feat = x @ W_down + b_down   (M=8192, N=256, K=1024)
  gemm_bias<<<dim3(Dsc / 64, M / 64), blk, 0, stream>>>(
      x, Wd, bd, nullptr, feat, M, Dsc, Dc);

  // sequential fast-weight scan -> preds  (1024 independent wave-chains)
  ttt_scan<<<dim3(Bc * Dsc / 4), blk, 0, stream>>>(feat, preds);

  // out = preds @ W_up + b_up + x   (M=8192, N=1024, K=256)
  gemm_bias<<<dim3(Dc / 64, M / 64), blk, 0, stream>>>(
      preds, Wu, bu, x, out, M, Dc, Dsc);
}

// Round 2
// 663.162 us; speedup vs baseline: 1.3911x; 1.2261x over previous
//
#include <hip/hip_runtime.h>

#define LR 0.01f

// Problem constants (from reference setup_inputs): B=4, S=2048, D=1024, Ds=256
constexpr int Bc  = 4;
constexpr int Sc  = 2048;
constexpr int Dc  = 1024;
constexpr int Dsc = 256;

// ---------------------------------------------------------------------------
// Tiled fp32 GEMM:  C[M,N] = A[M,K] @ Bm[K,N] + bias[N] (+ resid[M,N] if given)
// Block: 256 threads, 64x64 tile, BK=16, 4x4 micro-tile per thread.
// ---------------------------------------------------------------------------
__global__ __launch_bounds__(256) void gemm_bias(
    const float* __restrict__ A, const float* __restrict__ Bm,
    const float* __restrict__ bias, const float* __restrict__ resid,
    float* __restrict__ C, int M, int N, int K) {
  constexpr int BM = 64, BN = 64, BK = 16;
  __shared__ float As[BK][BM + 4];
  __shared__ float Bs[BK][BN + 4];

  const int bm = blockIdx.y * BM;
  const int bn = blockIdx.x * BN;
  const int tx = threadIdx.x & 15;   // 0..15 -> 4 cols each
  const int ty = threadIdx.x >> 4;   // 0..15 -> 4 rows each

  float acc[4][4] = {};

  for (int k0 = 0; k0 < K; k0 += BK) {
    // Load A tile: rows bm..bm+63, cols k0..k0+15  (k fastest -> 64B segments)
    for (int i = threadIdx.x; i < BM * BK; i += 256) {
      int m = i >> 4, k = i & 15;
      As[k][m] = A[(size_t)(bm + m) * K + k0 + k];
    }
    // Load B tile: rows k0..k0+15, cols bn..bn+63 (n fastest -> coalesced)
    for (int i = threadIdx.x; i < BK * BN; i += 256) {
      int k = i >> 6, n = i & 63;
      Bs[k][n] = Bm[(size_t)(k0 + k) * N + bn + n];
    }
    __syncthreads();
#pragma unroll
    for (int k = 0; k < BK; ++k) {
      float a[4], bb[4];
#pragma unroll
      for (int i = 0; i < 4; ++i) a[i] = As[k][ty * 4 + i];
#pragma unroll
      for (int j = 0; j < 4; ++j) bb[j] = Bs[k][tx * 4 + j];
#pragma unroll
      for (int i = 0; i < 4; ++i)
#pragma unroll
        for (int j = 0; j < 4; ++j) acc[i][j] += a[i] * bb[j];
    }
    __syncthreads();
  }

#pragma unroll
  for (int i = 0; i < 4; ++i) {
    int m = bm + ty * 4 + i;
#pragma unroll
    for (int j = 0; j < 4; ++j) {
      int n = bn + tx * 4 + j;
      float v = acc[i][j] + bias[n];
      if (resid) v += resid[(size_t)m * N + n];
      C[(size_t)m * N + n] = v;
    }
  }
}

// ---------------------------------------------------------------------------
// TTT scan. 1024 independent sequential chains (one per (b, output-col j)),
// one wave per chain; the 256-float W-column lives in 4 VGPRs per lane.
//
// v3 changes (v2 measured 671 cyc/step; compute chain is only ~120 cyc, the
// remaining ~550 cyc was exposed global-load latency):
//   - XCD-locality blockIdx swizzle: all 32 blocks on an XCD work the SAME
//     batch b -> its 2MB feat slice lives in that XCD's 4MB L2; loads become
//     ~200cyc L2 hits instead of ~500-900cyc L3/HBM first-touches.
//   - prefetch distance 8 (8 named register quads, fully static, unroll x8):
//     coverage = 7 steps of work >= worst-case load latency.
//   - DPP reduction retained from v2 (row_shr 1/2/4/8 + row_bcast 15/31 +
//     readlane 63), slot rotation so f_j = readlane(f0, jl).
// ---------------------------------------------------------------------------

template <int CTRL, int RM>
__device__ __forceinline__ float dpp_sum(float v) {
  int moved = __builtin_amdgcn_update_dpp(0, __float_as_int(v), CTRL, RM, 0xF, false);
  return v + __int_as_float(moved);
}

__global__ __launch_bounds__(256) void ttt_scan(const float* __restrict__ feat,
                                                float* __restrict__ preds) {
  const int lane = threadIdx.x & 63;
  const int wave = threadIdx.x >> 6;

  // XCD-locality swizzle: assume round-robin block->XCD dispatch (bi & 7).
  // XCDs {0,1} -> b=0, {2,3} -> b=1, {4,5} -> b=2, {6,7} -> b=3.
  // Correct (bijective) for any dispatch mapping; only locality depends on it.
  const int bi  = blockIdx.x;            // 0..255
  const int xcd = bi & 7;
  const int b   = xcd >> 1;              // 0..3
  const int q   = ((bi >> 3) << 1) | (xcd & 1);  // 0..63 group-of-4 within b
  const int j   = (q << 2) | wave;       // 0..255
  const int jl = j & 63;
  const int jw = j >> 6;

  // Rotated slot offsets: slot m holds f[lane + o_m]; slot 0 contains the
  // 64-group that includes index j, so f_j == readlane(f0, jl).
  const int o0 = 64 * ((jw + 0) & 3);
  const int o1 = 64 * ((jw + 1) & 3);
  const int o2 = 64 * ((jw + 2) & 3);
  const int o3 = 64 * ((jw + 3) & 3);

  const float* fb = feat + (size_t)b * Sc * Dsc + lane;
  float* pb = preds + (size_t)b * Sc * Dsc + j;

  float w0 = 0.f, w1 = 0.f, w2 = 0.f, w3 = 0.f;

  // Preload rows t = 0..7 (prefetch distance 8), named register quads only
  // (rule: no runtime-indexed register arrays -> scratch).
  float r00, r01, r02, r03, r10, r11, r12, r13, r20, r21, r22, r23;
  float r30, r31, r32, r33, r40, r41, r42, r43, r50, r51, r52, r53;
  float r60, r61, r62, r63, r70, r71, r72, r73;
#define TTT_LOAD(T, F0, F1, F2, F3)                  \
  {                                                  \
    const float* fr = fb + (size_t)(T) * Dsc;        \
    F0 = fr[o0]; F1 = fr[o1]; F2 = fr[o2]; F3 = fr[o3]; \
  }
  TTT_LOAD(0, r00, r01, r02, r03);
  TTT_LOAD(1, r10, r11, r12, r13);
  TTT_LOAD(2, r20, r21, r22, r23);
  TTT_LOAD(3, r30, r31, r32, r33);
  TTT_LOAD(4, r40, r41, r42, r43);
  TTT_LOAD(5, r50, r51, r52, r53);
  TTT_LOAD(6, r60, r61, r62, r63);
  TTT_LOAD(7, r70, r71, r72, r73);

#define TTT_STEP(T, F0, F1, F2, F3)                                            \
  {                                                                            \
    float f0 = F0, f1 = F1, f2 = F2, f3 = F3;                                  \
    if ((T) + 8 < Sc) { /* prefetch row T+8 into this buffer set */            \
      TTT_LOAD((T) + 8, F0, F1, F2, F3);                                       \
    }                                                                          \
    /* pred_j = f_t . w_col  (2-level FMA tree, then DPP reduce to lane 63) */ \
    float qq = fmaf(f1, w1, f0 * w0) + fmaf(f3, w3, f2 * w2);                  \
    qq = dpp_sum<0x111, 0xF>(qq); /* row_shr:1  */                             \
    qq = dpp_sum<0x112, 0xF>(qq); /* row_shr:2  */                             \
    qq = dpp_sum<0x114, 0xF>(qq); /* row_shr:4  */                             \
    qq = dpp_sum<0x118, 0xF>(qq); /* row_shr:8  */                             \
    qq = dpp_sum<0x142, 0xA>(qq); /* row_bcast:15 -> lane31/63 = half sums */  \
    qq = dpp_sum<0x143, 0xC>(qq); /* row_bcast:31 -> lane63 = full sum */      \
    float p  = __int_as_float(__builtin_amdgcn_readlane(__float_as_int(qq), 63)); \
    float fj = __int_as_float(__builtin_amdgcn_readlane(__float_as_int(f0), jl)); \
    float err = LR * (p - fj);                                                 \
    if (lane == 0) pb[(size_t)(T)*Dsc] = p;                                    \
    w0 = fmaf(-err, f0, w0);                                                   \
    w1 = fmaf(-err, f1, w1);                                                   \
    w2 = fmaf(-err, f2, w2);                                                   \
    w3 = fmaf(-err, f3, w3);                                                   \
  }

  for (int t0 = 0; t0 < Sc; t0 += 8) {
    TTT_STEP(t0 + 0, r00, r01, r02, r03);
    TTT_STEP(t0 + 1, r10, r11, r12, r13);
    TTT_STEP(t0 + 2, r20, r21, r22, r23);
    TTT_STEP(t0 + 3, r30, r31, r32, r33);
    TTT_STEP(t0 + 4, r40, r41, r42, r43);
    TTT_STEP(t0 + 5, r50, r51, r52, r53);
    TTT_STEP(t0 + 6, r60, r61, r62, r63);
    TTT_STEP(t0 + 7, r70, r71, r72, r73);
  }
#undef TTT_STEP
#undef TTT_LOAD
}

extern "C" void kernel_launch(void* const* d_in, const int* in_sizes, int n_in,
                              void* d_out, int out_size, void* d_ws, size_t ws_size,
                              hipStream_t stream) {
  const float* x  = (const float*)d_in[0];  // (B,S,D)
  const float* Wd = (const float*)d_in[1];  // (D,Ds)
  const float* bd = (const float*)d_in[2];  // (Ds)
  const float* Wu = (const float*)d_in[3];  // (Ds,D)
  const float* bu = (const float*)d_in[4];  // (D)
  float* out = (float*)d_out;               // (B,S,D)

  float* feat  = (float*)d_ws;                        // B*S*Ds f32 = 8 MB
  float* preds = feat + (size_t)Bc * Sc * Dsc;        // B*S*Ds f32 = 8 MB

  const int M = Bc * Sc;  // 8192
  dim3 blk(256);

  // feat = x @ W_down + b_down   (M=8192, N=256, K=1024)
  gemm_bias<<<dim3(Dsc / 64, M / 64), blk, 0, stream>>>(
      x, Wd, bd, nullptr, feat, M, Dsc, Dc);

  // sequential fast-weight scan -> preds  (1024 independent wave-chains)
  ttt_scan<<<dim3(Bc * Dsc / 4), blk, 0, stream>>>(feat, preds);

  // out = preds @ W_up + b_up + x   (M=8192, N=1024, K=256)
  gemm_bias<<<dim3(Dc / 64, M / 64), blk, 0, stream>>>(
      preds, Wu, bu, x, out, M, Dc, Dsc);
}

// Round 3
// 517.443 us; speedup vs baseline: 1.7829x; 1.2816x over previous
//
#include <hip/hip_runtime.h>

#define LR 0.01f

// Problem constants (from reference setup_inputs): B=4, S=2048, D=1024, Ds=256
constexpr int Bc  = 4;
constexpr int Sc  = 2048;
constexpr int Dc  = 1024;
constexpr int Dsc = 256;

// ---------------------------------------------------------------------------
// Tiled fp32 GEMM:  C[M,N] = A[M,K] @ Bm[K,N] + bias[N] (+ resid[M,N] if given)
// Block: 256 threads, 64x64 tile, BK=16, 4x4 micro-tile per thread.
// ---------------------------------------------------------------------------
__global__ __launch_bounds__(256) void gemm_bias(
    const float* __restrict__ A, const float* __restrict__ Bm,
    const float* __restrict__ bias, const float* __restrict__ resid,
    float* __restrict__ C, int M, int N, int K) {
  constexpr int BM = 64, BN = 64, BK = 16;
  __shared__ float As[BK][BM + 4];
  __shared__ float Bs[BK][BN + 4];

  const int bm = blockIdx.y * BM;
  const int bn = blockIdx.x * BN;
  const int tx = threadIdx.x & 15;   // 0..15 -> 4 cols each
  const int ty = threadIdx.x >> 4;   // 0..15 -> 4 rows each

  float acc[4][4] = {};

  for (int k0 = 0; k0 < K; k0 += BK) {
    // Load A tile: rows bm..bm+63, cols k0..k0+15  (k fastest -> 64B segments)
    for (int i = threadIdx.x; i < BM * BK; i += 256) {
      int m = i >> 4, k = i & 15;
      As[k][m] = A[(size_t)(bm + m) * K + k0 + k];
    }
    // Load B tile: rows k0..k0+15, cols bn..bn+63 (n fastest -> coalesced)
    for (int i = threadIdx.x; i < BK * BN; i += 256) {
      int k = i >> 6, n = i & 63;
      Bs[k][n] = Bm[(size_t)(k0 + k) * N + bn + n];
    }
    __syncthreads();
#pragma unroll
    for (int k = 0; k < BK; ++k) {
      float a[4], bb[4];
#pragma unroll
      for (int i = 0; i < 4; ++i) a[i] = As[k][ty * 4 + i];
#pragma unroll
      for (int j = 0; j < 4; ++j) bb[j] = Bs[k][tx * 4 + j];
#pragma unroll
      for (int i = 0; i < 4; ++i)
#pragma unroll
        for (int j = 0; j < 4; ++j) acc[i][j] += a[i] * bb[j];
    }
    __syncthreads();
  }

#pragma unroll
  for (int i = 0; i < 4; ++i) {
    int m = bm + ty * 4 + i;
#pragma unroll
    for (int j = 0; j < 4; ++j) {
      int n = bn + tx * 4 + j;
      float v = acc[i][j] + bias[n];
      if (resid) v += resid[(size_t)m * N + n];
      C[(size_t)m * N + n] = v;
    }
  }
}

// ---------------------------------------------------------------------------
// TTT scan. 1024 independent sequential chains (one per (b, output-col j)),
// one wave per chain; the 256-float W-column lives in 4 VGPRs per lane.
//
// v4: v3's 8-deep prefetch was COLLAPSED by the compiler (VGPR_Count=36 --
// cannot hold 32 prefetch floats), re-exposing ~370cyc load latency/step.
// Fix: ping-pong register banks of 8 rows each, with
// __builtin_amdgcn_sched_barrier(0) fences so the load group cannot be sunk
// below the compute group that follows it. Coverage = 8 steps (~700cyc) per
// bank >= worst-case L2/L3 latency. Waitcnt pass emits counted vmcnt (never
// a drain) since it runs after scheduling.
//   - DPP reduction retained (row_shr 1/2/4/8 + row_bcast 15/31 + readlane 63)
//   - slot rotation so f_j = readlane(F0, jl)
//   - XCD-locality swizzle retained (FETCH_SIZE 32.8MB -> 8.2MB, verified)
// ---------------------------------------------------------------------------

template <int CTRL, int RM>
__device__ __forceinline__ float dpp_sum(float v) {
  int moved = __builtin_amdgcn_update_dpp(0, __float_as_int(v), CTRL, RM, 0xF, false);
  return v + __int_as_float(moved);
}

__global__ __launch_bounds__(256) void ttt_scan(const float* __restrict__ feat,
                                                float* __restrict__ preds) {
  const int lane = threadIdx.x & 63;
  const int wave = threadIdx.x >> 6;

  // XCD-locality swizzle: XCDs {0,1}->b=0, {2,3}->b=1, {4,5}->b=2, {6,7}->b=3.
  // Bijective for any dispatch mapping; only locality depends on it.
  const int bi  = blockIdx.x;                    // 0..255
  const int xcd = bi & 7;
  const int b   = xcd >> 1;                      // 0..3
  const int q   = ((bi >> 3) << 1) | (xcd & 1);  // 0..63 group-of-4 within b
  const int j   = (q << 2) | wave;               // 0..255
  const int jl  = j & 63;
  const int jw  = j >> 6;

  // Rotated slot offsets: slot m holds f[lane + o_m]; slot 0 contains the
  // 64-group that includes index j, so f_j == readlane(F0, jl).
  const int o0 = 64 * ((jw + 0) & 3);
  const int o1 = 64 * ((jw + 1) & 3);
  const int o2 = 64 * ((jw + 2) & 3);
  const int o3 = 64 * ((jw + 3) & 3);

  const float* fb = feat + (size_t)b * Sc * Dsc + lane;
  float* pout = preds + (size_t)b * Sc * Dsc + j;

  float w0 = 0.f, w1 = 0.f, w2 = 0.f, w3 = 0.f;

  // Two ping-pong banks of 8 rows x 4 slots, all named scalars (rule: no
  // runtime-indexed register arrays -> scratch).
  float A00, A01, A02, A03, A10, A11, A12, A13, A20, A21, A22, A23;
  float A30, A31, A32, A33, A40, A41, A42, A43, A50, A51, A52, A53;
  float A60, A61, A62, A63, A70, A71, A72, A73;
  float C00, C01, C02, C03, C10, C11, C12, C13, C20, C21, C22, C23;
  float C30, C31, C32, C33, C40, C41, C42, C43, C50, C51, C52, C53;
  float C60, C61, C62, C63, C70, C71, C72, C73;

#define LDR(T, F0, F1, F2, F3)                          \
  do {                                                  \
    const float* fr_ = fb + (size_t)(T) * Dsc;          \
    F0 = fr_[o0]; F1 = fr_[o1]; F2 = fr_[o2]; F3 = fr_[o3]; \
  } while (0)

#define LOADGRP_A(T)                       \
  LDR((T) + 0, A00, A01, A02, A03);        \
  LDR((T) + 1, A10, A11, A12, A13);        \
  LDR((T) + 2, A20, A21, A22, A23);        \
  LDR((T) + 3, A30, A31, A32, A33);        \
  LDR((T) + 4, A40, A41, A42, A43);        \
  LDR((T) + 5, A50, A51, A52, A53);        \
  LDR((T) + 6, A60, A61, A62, A63);        \
  LDR((T) + 7, A70, A71, A72, A73)

#define LOADGRP_C(T)                       \
  LDR((T) + 0, C00, C01, C02, C03);        \
  LDR((T) + 1, C10, C11, C12, C13);        \
  LDR((T) + 2, C20, C21, C22, C23);        \
  LDR((T) + 3, C30, C31, C32, C33);        \
  LDR((T) + 4, C40, C41, C42, C43);        \
  LDR((T) + 5, C50, C51, C52, C53);        \
  LDR((T) + 6, C60, C61, C62, C63);        \
  LDR((T) + 7, C70, C71, C72, C73)

#define TTT_STEP(T, F0, F1, F2, F3)                                            \
  {                                                                            \
    /* pred_j = f_t . w_col  (2-level FMA tree, then DPP reduce to lane 63) */ \
    float qq = fmaf(F1, w1, F0 * w0) + fmaf(F3, w3, F2 * w2);                  \
    qq = dpp_sum<0x111, 0xF>(qq); /* row_shr:1  */                             \
    qq = dpp_sum<0x112, 0xF>(qq); /* row_shr:2  */                             \
    qq = dpp_sum<0x114, 0xF>(qq); /* row_shr:4  */                             \
    qq = dpp_sum<0x118, 0xF>(qq); /* row_shr:8  */                             \
    qq = dpp_sum<0x142, 0xA>(qq); /* row_bcast:15 -> lane31/63 = half sums */  \
    qq = dpp_sum<0x143, 0xC>(qq); /* row_bcast:31 -> lane63 = full sum  */     \
    float p  = __int_as_float(__builtin_amdgcn_readlane(__float_as_int(qq), 63)); \
    float fj = __int_as_float(__builtin_amdgcn_readlane(__float_as_int(F0), jl)); \
    float err = LR * (p - fj);                                                 \
    if (lane == 0) pout[(size_t)(T)*Dsc] = p;                                  \
    w0 = fmaf(-err, F0, w0);                                                   \
    w1 = fmaf(-err, F1, w1);                                                   \
    w2 = fmaf(-err, F2, w2);                                                   \
    w3 = fmaf(-err, F3, w3);                                                   \
  }

  // Prologue: rows 0..7 into bank A.
  LOADGRP_A(0);

  for (int t0 = 0; t0 < Sc; t0 += 16) {
    // Prefetch rows t0+8..t0+15 into bank C (always in range: t0+15 <= 2047).
    LOADGRP_C(t0 + 8);
    __builtin_amdgcn_sched_barrier(0);  // loads above may not sink below

    TTT_STEP(t0 + 0, A00, A01, A02, A03);
    TTT_STEP(t0 + 1, A10, A11, A12, A13);
    TTT_STEP(t0 + 2, A20, A21, A22, A23);
    TTT_STEP(t0 + 3, A30, A31, A32, A33);
    TTT_STEP(t0 + 4, A40, A41, A42, A43);
    TTT_STEP(t0 + 5, A50, A51, A52, A53);
    TTT_STEP(t0 + 6, A60, A61, A62, A63);
    TTT_STEP(t0 + 7, A70, A71, A72, A73);

    // Prefetch rows t0+16..t0+23 into bank A (skip on final iteration).
    if (t0 + 16 < Sc) {
      LOADGRP_A(t0 + 16);
    }
    __builtin_amdgcn_sched_barrier(0);  // loads above may not sink below

    TTT_STEP(t0 + 8,  C00, C01, C02, C03);
    TTT_STEP(t0 + 9,  C10, C11, C12, C13);
    TTT_STEP(t0 + 10, C20, C21, C22, C23);
    TTT_STEP(t0 + 11, C30, C31, C32, C33);
    TTT_STEP(t0 + 12, C40, C41, C42, C43);
    TTT_STEP(t0 + 13, C50, C51, C52, C53);
    TTT_STEP(t0 + 14, C60, C61, C62, C63);
    TTT_STEP(t0 + 15, C70, C71, C72, C73);
  }
#undef TTT_STEP
#undef LOADGRP_A
#undef LOADGRP_C
#undef LDR
}

extern "C" void kernel_launch(void* const* d_in, const int* in_sizes, int n_in,
                              void* d_out, int out_size, void* d_ws, size_t ws_size,
                              hipStream_t stream) {
  const float* x  = (const float*)d_in[0];  // (B,S,D)
  const float* Wd = (const float*)d_in[1];  // (D,Ds)
  const float* bd = (const float*)d_in[2];  // (Ds)
  const float* Wu = (const float*)d_in[3];  // (Ds,D)
  const float* bu = (const float*)d_in[4];  // (D)
  float* out = (float*)d_out;               // (B,S,D)

  float* feat  = (float*)d_ws;                        // B*S*Ds f32 = 8 MB
  float* preds = feat + (size_t)Bc * Sc * Dsc;        // B*S*Ds f32 = 8 MB

  const int M = Bc * Sc;  // 8192
  dim3 blk(256);

  // feat = x @ W_down + b_down   (M=8192, N=256, K=1024)
  gemm_bias<<<dim3(Dsc / 64, M / 64), blk, 0, stream>>>(
      x, Wd, bd, nullptr, feat, M, Dsc, Dc);

  // sequential fast-weight scan -> preds  (1024 independent wave-chains)
  ttt_scan<<<dim3(Bc * Dsc / 4), blk, 0, stream>>>(feat, preds);

  // out = preds @ W_up + b_up + x   (M=8192, N=1024, K=256)
  gemm_bias<<<dim3(Dc / 64, M / 64), blk, 0, stream>>>(
      preds, Wu, bu, x, out, M, Dc, Dsc);
}

// Round 5
// 436.378 us; speedup vs baseline: 2.1141x; 1.1858x over previous
//
#include <hip/hip_runtime.h>

#define LR 0.01f

// Problem constants (from reference setup_inputs): B=4, S=2048, D=1024, Ds=256
constexpr int Bc  = 4;
constexpr int Sc  = 2048;
constexpr int Dc  = 1024;
constexpr int Dsc = 256;

// ---------------------------------------------------------------------------
// Tiled fp32 GEMM:  C[M,N] = A[M,K] @ Bm[K,N] + bias[N] (+ resid[M,N] if given)
// Block: 256 threads, 64x64 tile, BK=16, 4x4 micro-tile per thread.
// ---------------------------------------------------------------------------
__global__ __launch_bounds__(256) void gemm_bias(
    const float* __restrict__ A, const float* __restrict__ Bm,
    const float* __restrict__ bias, const float* __restrict__ resid,
    float* __restrict__ C, int M, int N, int K) {
  constexpr int BM = 64, BN = 64, BK = 16;
  __shared__ float As[BK][BM + 4];
  __shared__ float Bs[BK][BN + 4];

  const int bm = blockIdx.y * BM;
  const int bn = blockIdx.x * BN;
  const int tx = threadIdx.x & 15;   // 0..15 -> 4 cols each
  const int ty = threadIdx.x >> 4;   // 0..15 -> 4 rows each

  float acc[4][4] = {};

  for (int k0 = 0; k0 < K; k0 += BK) {
    // Load A tile: rows bm..bm+63, cols k0..k0+15  (k fastest -> 64B segments)
    for (int i = threadIdx.x; i < BM * BK; i += 256) {
      int m = i >> 4, k = i & 15;
      As[k][m] = A[(size_t)(bm + m) * K + k0 + k];
    }
    // Load B tile: rows k0..k0+15, cols bn..bn+63 (n fastest -> coalesced)
    for (int i = threadIdx.x; i < BK * BN; i += 256) {
      int k = i >> 6, n = i & 63;
      Bs[k][n] = Bm[(size_t)(k0 + k) * N + bn + n];
    }
    __syncthreads();
#pragma unroll
    for (int k = 0; k < BK; ++k) {
      float a[4], bb[4];
#pragma unroll
      for (int i = 0; i < 4; ++i) a[i] = As[k][ty * 4 + i];
#pragma unroll
      for (int j = 0; j < 4; ++j) bb[j] = Bs[k][tx * 4 + j];
#pragma unroll
      for (int i = 0; i < 4; ++i)
#pragma unroll
        for (int j = 0; j < 4; ++j) acc[i][j] += a[i] * bb[j];
    }
    __syncthreads();
  }

#pragma unroll
  for (int i = 0; i < 4; ++i) {
    int m = bm + ty * 4 + i;
#pragma unroll
    for (int j = 0; j < 4; ++j) {
      int n = bn + tx * 4 + j;
      float v = acc[i][j] + bias[n];
      if (resid) v += resid[(size_t)m * N + n];
      C[(size_t)m * N + n] = v;
    }
  }
}

// ---------------------------------------------------------------------------
// TTT scan. 1024 independent sequential chains (one per (b, output-col j)),
// one wave per chain; the 256-float W-column lives in 4 VGPRs per lane.
//
// v6 (= v5 with the writelane fixed): v4's register prefetch banks couldn't
// be held by the RA (VGPR=48), leaving ~230cyc/step exposed load latency.
// Fix: the block's 4 waves (4 chains, SAME batch b) share feat rows -> stage
// feat in LDS via global_load_lds (width 16, zero VGPR cost, async DMA),
// double-buffered 64-row chunks (2 x 64KB). Chunk handoff = m201 pattern:
// barrier -> stage(c+2) -> counted s_waitcnt vmcnt(16) -> barrier (never a
// drain in the main loop). Per step: 5 ds_read_b32 off one addr reg
// (imm offsets after unroll; 2-way bank alias free; FJ = same-address
// broadcast of f[j], killing the second readlane + slot rotation).
// preds collected per-lane via predicated select (v_cmp+v_cndmask; the
// writelane builtin does not exist on this ROCm), one store per chunk.
//   - DPP reduce retained (row_shr 1/2/4/8 + row_bcast 15/31 + readlane 63)
//   - XCD-locality swizzle retained (FETCH_SIZE 32.8MB -> 8.2MB, verified)
// ---------------------------------------------------------------------------

template <int CTRL, int RM>
__device__ __forceinline__ float dpp_sum(float v) {
  int moved = __builtin_amdgcn_update_dpp(0, __float_as_int(v), CTRL, RM, 0xF, false);
  return v + __int_as_float(moved);
}

__device__ __forceinline__ void async_copy16(const float* g, float* l) {
  __builtin_amdgcn_global_load_lds(
      (const __attribute__((address_space(1))) unsigned int*)g,
      (__attribute__((address_space(3))) unsigned int*)l, 16, 0, 0);
}

constexpr int RCH = 64;        // rows per LDS chunk (64 x 1KB = 64KB/buffer)
constexpr int NCH = Sc / RCH;  // 32 chunks

__global__ __launch_bounds__(256) void ttt_scan(const float* __restrict__ feat,
                                                float* __restrict__ preds) {
  const int lane = threadIdx.x & 63;
  const int wave = threadIdx.x >> 6;

  // XCD-locality swizzle: XCDs {0,1}->b=0, {2,3}->b=1, {4,5}->b=2, {6,7}->b=3.
  const int bi  = blockIdx.x;                    // 0..255
  const int xcd = bi & 7;
  const int b   = xcd >> 1;                      // 0..3
  const int q   = ((bi >> 3) << 1) | (xcd & 1);  // 0..63 group-of-4 within b
  const int j   = (q << 2) | wave;               // 0..255

  __shared__ float lds[2][RCH * Dsc];  // 128 KB

  const float* fb0 = feat + (size_t)b * Sc * Dsc;
  float* pb0 = preds + (size_t)b * Sc * Dsc + j;

  float w0 = 0.f, w1 = 0.f, w2 = 0.f, w3 = 0.f;
  float vp = 0.f;  // 64 per-chunk preds, slot t in lane t

// Each wave stages 16 rows of a 64-row chunk: one global_load_lds(16B) per
// row (64 lanes x 16B = 1KB = one row). LDS dest is wave-uniform base +
// lane*16 (hardware), matching the linear row-major layout exactly.
#define STAGE_CHUNK(BUFSEL, T0)                                         \
  {                                                                     \
    _Pragma("unroll")                                                   \
    for (int r_ = 0; r_ < 16; ++r_) {                                   \
      const int row_ = (wave << 4) | r_;                                \
      async_copy16(fb0 + (size_t)((T0) + row_) * Dsc + (lane << 2),     \
                   &lds[BUFSEL][row_ * Dsc]);                           \
    }                                                                   \
  }

// Read one row's 4 per-lane slots + the wave-uniform f[j] broadcast.
#define DSR5(CB, R, F0, F1, F2, F3, FJ)          \
  {                                              \
    const int rb_ = (R) * Dsc;                   \
    F0 = lds[CB][rb_ + lane];                    \
    F1 = lds[CB][rb_ + lane + 64];               \
    F2 = lds[CB][rb_ + lane + 128];              \
    F3 = lds[CB][rb_ + lane + 192];               \
    FJ = lds[CB][rb_ + j];                       \
  }

#define TTT_STEP(SLOT, F0, F1, F2, F3, FJ)                                     \
  {                                                                            \
    /* pred_j = f_t . w_col  (2-level FMA tree, then DPP reduce to lane 63) */ \
    float qq = fmaf(F1, w1, F0 * w0) + fmaf(F3, w3, F2 * w2);                  \
    qq = dpp_sum<0x111, 0xF>(qq); /* row_shr:1 */                              \
    qq = dpp_sum<0x112, 0xF>(qq); /* row_shr:2 */                              \
    qq = dpp_sum<0x114, 0xF>(qq); /* row_shr:4 */                              \
    qq = dpp_sum<0x118, 0xF>(qq); /* row_shr:8 */                              \
    qq = dpp_sum<0x142, 0xA>(qq); /* row_bcast:15 */                           \
    qq = dpp_sum<0x143, 0xC>(qq); /* row_bcast:31 -> lane63 = full sum */      \
    float p = __int_as_float(__builtin_amdgcn_readlane(__float_as_int(qq), 63)); \
    float err = LR * (p - FJ);                                                 \
    vp = (lane == (SLOT)) ? p : vp; /* v_cmp+v_cndmask, off the w-chain */     \
    w0 = fmaf(-err, F0, w0);                                                   \
    w1 = fmaf(-err, F1, w1);                                                   \
    w2 = fmaf(-err, F2, w2);                                                   \
    w3 = fmaf(-err, F3, w3);                                                   \
  }

  // Prologue: stage chunks 0 and 1; wait for chunk 0 (16 newest may remain).
  STAGE_CHUNK(0, 0);
  STAGE_CHUNK(1, RCH);
  asm volatile("s_waitcnt vmcnt(16)" ::: "memory");
  __builtin_amdgcn_s_barrier();
  __builtin_amdgcn_sched_barrier(0);

  for (int c = 0; c < NCH; ++c) {
    const int cb = c & 1;

    float X00, X01, X02, X03, XJ0, X10, X11, X12, X13, XJ1;
    float X20, X21, X22, X23, XJ2, X30, X31, X32, X33, XJ3;
    float Y00, Y01, Y02, Y03, YJ0, Y10, Y11, Y12, Y13, YJ1;
    float Y20, Y21, Y22, Y23, YJ2, Y30, Y31, Y32, Y33, YJ3;

    // Chunk prologue: rows 0..3 into bank X.
    DSR5(cb, 0, X00, X01, X02, X03, XJ0);
    DSR5(cb, 1, X10, X11, X12, X13, XJ1);
    DSR5(cb, 2, X20, X21, X22, X23, XJ2);
    DSR5(cb, 3, X30, X31, X32, X33, XJ3);
    __builtin_amdgcn_sched_barrier(0);

#pragma unroll
    for (int s = 0; s < RCH; s += 8) {
      DSR5(cb, s + 4, Y00, Y01, Y02, Y03, YJ0);
      DSR5(cb, s + 5, Y10, Y11, Y12, Y13, YJ1);
      DSR5(cb, s + 6, Y20, Y21, Y22, Y23, YJ2);
      DSR5(cb, s + 7, Y30, Y31, Y32, Y33, YJ3);
      __builtin_amdgcn_sched_barrier(0);

      TTT_STEP(s + 0, X00, X01, X02, X03, XJ0);
      TTT_STEP(s + 1, X10, X11, X12, X13, XJ1);
      TTT_STEP(s + 2, X20, X21, X22, X23, XJ2);
      TTT_STEP(s + 3, X30, X31, X32, X33, XJ3);

      if (s + 8 < RCH) {
        DSR5(cb, s + 8,  X00, X01, X02, X03, XJ0);
        DSR5(cb, s + 9,  X10, X11, X12, X13, XJ1);
        DSR5(cb, s + 10, X20, X21, X22, X23, XJ2);
        DSR5(cb, s + 11, X30, X31, X32, X33, XJ3);
      }
      __builtin_amdgcn_sched_barrier(0);

      TTT_STEP(s + 4, Y00, Y01, Y02, Y03, YJ0);
      TTT_STEP(s + 5, Y10, Y11, Y12, Y13, YJ1);
      TTT_STEP(s + 6, Y20, Y21, Y22, Y23, YJ2);
      TTT_STEP(s + 7, Y30, Y31, Y32, Y33, YJ3);
    }

    // One store per chunk: lane t holds pred for row c*64+t.
    pb0[(size_t)(c * RCH + lane) * Dsc] = vp;

    // Chunk handoff (m201 pattern): all waves done reading lds[cb] ->
    // overwrite it with chunk c+2 -> counted wait (chunk c+1's 16 loads are
    // older than the 16 just issued) -> barrier makes c+1 visible to all.
    __builtin_amdgcn_s_barrier();
    if (c + 2 < NCH) {
      STAGE_CHUNK(cb, (c + 2) * RCH);
      asm volatile("s_waitcnt vmcnt(16)" ::: "memory");
    } else {
      asm volatile("s_waitcnt vmcnt(0)" ::: "memory");
    }
    __builtin_amdgcn_s_barrier();
    __builtin_amdgcn_sched_barrier(0);
  }
#undef TTT_STEP
#undef DSR5
#undef STAGE_CHUNK
}

extern "C" void kernel_launch(void* const* d_in, const int* in_sizes, int n_in,
                              void* d_out, int out_size, void* d_ws, size_t ws_size,
                              hipStream_t stream) {
  const float* x  = (const float*)d_in[0];  // (B,S,D)
  const float* Wd = (const float*)d_in[1];  // (D,Ds)
  const float* bd = (const float*)d_in[2];  // (Ds)
  const float* Wu = (const float*)d_in[3];  // (Ds,D)
  const float* bu = (const float*)d_in[4];  // (D)
  float* out = (float*)d_out;               // (B,S,D)

  float* feat  = (float*)d_ws;                        // B*S*Ds f32 = 8 MB
  float* preds = feat + (size_t)Bc * Sc * Dsc;        // B*S*Ds f32 = 8 MB

  const int M = Bc * Sc;  // 8192
  dim3 blk(256);

  // feat = x @ W_down + b_down   (M=8192, N=256, K=1024)
  gemm_bias<<<dim3(Dsc / 64, M / 64), blk, 0, stream>>>(
      x, Wd, bd, nullptr, feat, M, Dsc, Dc);

  // sequential fast-weight scan -> preds  (1024 independent wave-chains)
  ttt_scan<<<dim3(Bc * Dsc / 4), blk, 0, stream>>>(feat, preds);

  // out = preds @ W_up + b_up + x   (M=8192, N=1024, K=256)
  gemm_bias<<<dim3(Dc / 64, M / 64), blk, 0, stream>>>(
      preds, Wu, bu, x, out, M, Dc, Dsc);
}